// Round 7
// baseline (565.516 us; speedup 1.0000x reference)
//
#include <hip/hip_runtime.h>
#include <math.h>

#define NK 512                      // N_EMB
#define NPTS (32*64*64)             // 131072 points
#define NELEM (32*64*64*64)         // 8388608 elements of z

// flat d_out offsets (return order: loss, z_q, perplexity, encodings, codebook)
#define OFF_LOSS 0
#define OFF_ZQ   1
#define OFF_PERP (1 + NELEM)
#define OFF_ENC  (2 + NELEM)
#define OFF_CB   (2 + NELEM + (size_t)NPTS * NK)

// ws layout: [0,2048) hist int[512] | [2048,2056) lossAcc double |
//            [4096, +128KB) wTT f32[64 chunks][64 d][8 codes] | then bnd f32[512]

// ---- prep: wTT[(c*64+d)*8+j] = w[c*8+j][d]; bnd[k] = sum_d w[k][d]^2 (sequential d) ----
__global__ __launch_bounds__(256) void vq_prep(const float* __restrict__ wg,
                                               float* __restrict__ wTT,
                                               float* __restrict__ bnd) {
    __shared__ float tl[64 * 65];
    const int t = threadIdx.x;
    const int kbase = blockIdx.x * 64;          // 8 blocks x 64 codes
    #pragma unroll
    for (int it = 0; it < 16; ++it) {
        int i = it * 256 + t;
        int k = i >> 6, d = i & 63;
        tl[k * 65 + d] = wg[(size_t)(kbase + k) * 64 + d];
    }
    __syncthreads();
    #pragma unroll
    for (int it = 0; it < 16; ++it) {
        int i = it * 256 + t;
        int kk = i & 63, d = i >> 6;
        int k = kbase + kk;
        wTT[(size_t)((k >> 3) * 64 + d) * 8 + (k & 7)] = tl[kk * 65 + d];
    }
    if (t < 64) {
        float s = 0.f;
        #pragma unroll 4
        for (int d = 0; d < 64; ++d) {
            float v = tl[t * 65 + d];
            s = __fadd_rn(s, __fmul_rn(v, v));
        }
        bnd[kbase + t] = s;
    }
}

// Fused kernel: 512 blocks x 256 threads. wave = one (b,h) row, ALL 512 codes.
// lane = point. z in VGPRs (coalesced, no transpose, all indices compile-time).
// Codes via scalar pipe (wave-uniform wTT reads -> s_load + v_fmac v,s,v).
// Inner loop: zero LDS / zero vector-memory. No barriers anywhere.
__global__ __launch_bounds__(256, 2) void vq_fused(const float* __restrict__ zg,
                                                   const float* __restrict__ wg,
                                                   const float* __restrict__ wTT,
                                                   const float* __restrict__ bndg,
                                                   float* __restrict__ out,
                                                   int* __restrict__ hist,
                                                   double* __restrict__ lossAcc) {
    const int t = threadIdx.x;
    const int wave = t >> 6;
    const int lane = t & 63;
    const int r = blockIdx.x * 4 + wave;       // 2048 rows = (b,h)
    const int b = r >> 6;
    const int h = r & 63;
    const size_t base = (size_t)b * 262144 + (size_t)h * 64;   // + d*4096 + lane

    // ---- z row into registers: lane p gets z[b, d, h, p] (coalesced per d) ----
    float zreg[64];
    #pragma unroll
    for (int d = 0; d < 64; ++d)
        zreg[d] = zg[base + (size_t)d * 4096 + lane];

    // ---- a = sum_d z^2 (sequential d, mul+add — matches reference) ----
    float a = 0.f;
    #pragma unroll
    for (int d = 0; d < 64; ++d)
        a = __fadd_rn(a, __fmul_rn(zreg[d], zreg[d]));

    float best = INFINITY;
    int bidx = 0;

    #pragma unroll 1
    for (int cc = 0; cc < 64; ++cc) {
        const float* wrow = wTT + cc * 512;     // wave-uniform -> scalar loads
        float acc[8];
        #pragma unroll
        for (int j = 0; j < 8; ++j) acc[j] = 0.f;

        #pragma unroll
        for (int d = 0; d < 64; ++d) {
            const float zv = zreg[d];
            #pragma unroll
            for (int j = 0; j < 8; ++j)
                acc[j] = fmaf(zv, wrow[d * 8 + j], acc[j]);
        }

        // dist = fl(fl(a+b) - 2*dot); ascending k + strict < = first-index
        #pragma unroll
        for (int j = 0; j < 8; ++j) {
            float dist = __fsub_rn(__fadd_rn(a, bndg[cc * 8 + j]), 2.0f * acc[j]);
            int k = cc * 8 + j;
            if (dist < best) { best = dist; bidx = k; }
        }
    }

    // ---- codebook + histogram ----
    out[OFF_CB + (size_t)r * 64 + lane] = (float)bidx;
    atomicAdd(&hist[bidx], 1);

    // ---- z_q (straight-through) + loss partial (all indices compile-time) ----
    float lsum = 0.f;
    {
        float q[64];
        const float4* wr4 = (const float4*)(wg + (size_t)bidx * 64);  // per-lane gather (L1/L2)
        #pragma unroll
        for (int e = 0; e < 16; ++e) {
            float4 v = wr4[e];
            q[4 * e + 0] = v.x; q[4 * e + 1] = v.y;
            q[4 * e + 2] = v.z; q[4 * e + 3] = v.w;
        }
        float* zq = out + OFF_ZQ + base;
        #pragma unroll
        for (int d = 0; d < 64; ++d) {
            float zv = zreg[d];
            float diff = __fsub_rn(q[d], zv);
            lsum = __fadd_rn(lsum, __fmul_rn(diff, diff));
            zq[(size_t)d * 4096 + lane] = __fadd_rn(zv, diff);
        }
    }
    #pragma unroll
    for (int off = 32; off > 0; off >>= 1)
        lsum += __shfl_down(lsum, off);
    if (lane == 0)
        atomicAdd(lossAcc, (double)lsum);

    // ---- encodings: 64 one-hot rows, dense coalesced float4 (zreg dead here) ----
    {
        float* encb = out + OFF_ENC + ((size_t)r * 64) * 512;
        const int e0 = lane * 4;          // floats [e0,e0+4) and [256+e0, 256+e0+4)
        #pragma unroll 4
        for (int p = 0; p < 64; ++p) {
            int idx = __shfl(bidx, p);    // point p's winner, broadcast in-wave
            float* erow = encb + (size_t)p * 512;
            float4 A, B;
            A.x = (e0 + 0 == idx) ? 1.f : 0.f;
            A.y = (e0 + 1 == idx) ? 1.f : 0.f;
            A.z = (e0 + 2 == idx) ? 1.f : 0.f;
            A.w = (e0 + 3 == idx) ? 1.f : 0.f;
            B.x = (e0 + 256 == idx) ? 1.f : 0.f;
            B.y = (e0 + 257 == idx) ? 1.f : 0.f;
            B.z = (e0 + 258 == idx) ? 1.f : 0.f;
            B.w = (e0 + 259 == idx) ? 1.f : 0.f;
            *(float4*)(erow + e0) = A;
            *(float4*)(erow + 256 + e0) = B;
        }
    }
}

__global__ __launch_bounds__(512) void vq_finalize(const int* __restrict__ hist,
                                                   const double* __restrict__ lossAcc,
                                                   float* __restrict__ out) {
    __shared__ float sh[512];
    const int t = threadIdx.x;
    float p = (float)hist[t] / (float)NPTS;   // exact: /2^17
    sh[t] = __fmul_rn(p, logf(__fadd_rn(p, 1e-10f)));
    __syncthreads();
    for (int s = 256; s > 0; s >>= 1) {
        if (t < s) sh[t] += sh[t + s];
        __syncthreads();
    }
    if (t == 0) {
        float m = (float)(*lossAcc / (double)NELEM);
        out[OFF_LOSS] = __fadd_rn(m, __fmul_rn(0.25f, m));
        out[OFF_PERP] = expf(-sh[0]);
    }
}

extern "C" void kernel_launch(void* const* d_in, const int* in_sizes, int n_in,
                              void* d_out, int out_size, void* d_ws, size_t ws_size,
                              hipStream_t stream) {
    const float* z = (const float*)d_in[0];
    const float* w = (const float*)d_in[1];
    float* out = (float*)d_out;
    int* hist = (int*)d_ws;
    double* lossAcc = (double*)((char*)d_ws + 2048);
    float* wTT = (float*)((char*)d_ws + 4096);
    float* bnd = wTT + 64 * 512;

    (void)hipMemsetAsync(d_ws, 0, 4096, stream);
    vq_prep<<<8, 256, 0, stream>>>(w, wTT, bnd);
    vq_fused<<<512, 256, 0, stream>>>(z, w, wTT, bnd, out, hist, lossAcc);
    vq_finalize<<<1, 512, 0, stream>>>(hist, lossAcc, out);
}